// Round 1
// baseline (229.047 us; speedup 1.0000x reference)
//
#include <hip/hip_runtime.h>
#include <hip/hip_bf16.h>
#include <cstdint>

#define B_SIZE 4096
#define TWO_B  8192
#define DIM    512           // row length; fp8 => 512 bytes per row
#define NPAIRS 2080          // 64*65/2 upper-triangular tile pairs
// exp(x/t) = exp2(x * log2(e)/t), t = 0.5
#define EXP_SCALE 2.8853900817779268f
#define SCALE1 0x7F7F7F7F    // e8m0 scale = 2^0 = 1.0 in every byte

typedef __attribute__((ext_vector_type(4)))  float f32x4;
typedef __attribute__((ext_vector_type(16))) float f32x16;
typedef __attribute__((ext_vector_type(4)))  int   i32x4;
typedef __attribute__((ext_vector_type(8)))  int   i32x8;

// raw waitcnt: vmcnt(n) with lgkmcnt/expcnt unconstrained (gfx9 encoding)
#define WAITVM(n) __builtin_amdgcn_s_waitcnt(0xF70 | (n))
#define BARRIER() __builtin_amdgcn_s_barrier()

// ---------- helpers ----------
__device__ __forceinline__ void async16(const void* g, void* l) {
    __builtin_amdgcn_global_load_lds(
        (const __attribute__((address_space(1))) unsigned int*)g,
        (__attribute__((address_space(3))) unsigned int*)l,
        16, 0, 0);
}

// ---------- kernel 1: L2-normalize rows -> fp8 reps, fp32 positives, zero denom/out ----------
__global__ __launch_bounds__(256) void norm_pos_kernel(
    const float* __restrict__ emb_i, const float* __restrict__ emb_j,
    unsigned char* __restrict__ reps, float* __restrict__ pos,
    float* __restrict__ denom, float* __restrict__ out)
{
    __shared__ float sc[3][4];
    int b = blockIdx.x, t = threadIdx.x;
    if (b < 32) denom[b * 256 + t] = 0.0f;     // zero-init, visible at kernel boundary
    if (b == 32 && t == 0) out[0] = 0.0f;      // loss kernel accumulates atomically

    const float2* ri = (const float2*)(emb_i + (size_t)b * DIM);
    const float2* rj = (const float2*)(emb_j + (size_t)b * DIM);
    float2 xi = ri[t], xj = rj[t];
    float si = xi.x * xi.x + xi.y * xi.y;
    float sj = xj.x * xj.x + xj.y * xj.y;
    #pragma unroll
    for (int o = 32; o > 0; o >>= 1) { si += __shfl_down(si, o, 64); sj += __shfl_down(sj, o, 64); }
    int lane = t & 63, w = t >> 6;
    if (lane == 0) { sc[0][w] = si; sc[1][w] = sj; }
    __syncthreads();
    float ni2 = sc[0][0] + sc[0][1] + sc[0][2] + sc[0][3];
    float nj2 = sc[1][0] + sc[1][1] + sc[1][2] + sc[1][3];
    float rni = 1.0f / fmaxf(sqrtf(ni2), 1e-12f);
    float rnj = 1.0f / fmaxf(sqrtf(nj2), 1e-12f);
    float zix = xi.x * rni, ziy = xi.y * rni;
    float zjx = xj.x * rnj, zjy = xj.y * rnj;
    // pack 2 floats -> 2 OCP e4m3 bytes (HW cvt, gfx950)
    int pki = __builtin_amdgcn_cvt_pk_fp8_f32(zix, ziy, 0, false);
    int pkj = __builtin_amdgcn_cvt_pk_fp8_f32(zjx, zjy, 0, false);
    ((unsigned short*)(reps + (size_t)b * DIM))[t]            = (unsigned short)pki;
    ((unsigned short*)(reps + (size_t)(b + B_SIZE) * DIM))[t] = (unsigned short)pkj;
    float d = zix * zjx + ziy * zjy;
    #pragma unroll
    for (int o = 32; o > 0; o >>= 1) d += __shfl_down(d, o, 64);
    if (lane == 0) sc[2][w] = d;
    __syncthreads();
    if (t == 0) pos[b] = sc[2][0] + sc[2][1] + sc[2][2] + sc[2][3];
}

// ---------- kernel 2: symmetric fused R*R^T (MX-scaled fp8 MFMA, unit scales) ----------
// fp8 tiles: 128 rows x 64 B; row r = 4 pieces of 16 B, piece p stored at p ^ ((r^(r>>2))&3)
// (bank-group-bijective per 8-row stripe => full-wave b128 fragment reads hit the inherent
//  8-beat minimum, no extra conflicts). Double-buffered (32 KB LDS), vmcnt(4) + raw barriers.
// MFMA: v_mfma_scale_f32_32x32x64_f8f6f4 with e8m0 scales = 1.0 -> 2x the non-scaled fp8 rate,
// one MFMA per frag-pair per BK=64 slab. A/B frag: row = lane&31, k = (lane>>5)*32 + [0..31].
#define BM 128
#define BK 64
#define KITERS 8             // DIM / BK

__global__ __launch_bounds__(256) void sim_denom_kernel(
    const unsigned char* __restrict__ reps,
    const int* __restrict__ target,
    float* __restrict__ denom)
{
    __shared__ __align__(16) unsigned char As0[BM * BK];
    __shared__ __align__(16) unsigned char As1[BM * BK];
    __shared__ __align__(16) unsigned char Bs0[BM * BK];
    __shared__ __align__(16) unsigned char Bs1[BM * BK];

    int t = threadIdx.x;
    int id = blockIdx.x;

    // --- supertile swizzle: 4x4 supertiles of 16x16 tiles over the 64-tile triangle ---
    const int sI[10]  = {0,0,0,0,1,1,1,2,2,3};
    const int sJ[10]  = {0,1,2,3,1,2,3,2,3,3};
    const int off[11] = {0,136,392,648,904,1040,1296,1552,1688,1944,2080};
    int s = 0;
    while (off[s + 1] <= id) s++;
    int l = id - off[s];
    int u, v;
    if (sI[s] == sJ[s]) {                       // triangular 16x16: start(u)=u*(33-u)/2
        u = 0;
        while (((u + 1) * (32 - u)) / 2 <= l) u++;
        v = u + (l - (u * (33 - u)) / 2);
    } else { u = l >> 4; v = l & 15; }
    int bi = sI[s] * 16 + u;
    int bj = sJ[s] * 16 + v;
    int brow = bi * BM;
    int bcol = bj * BM;

    int wave = t >> 6, lane = t & 63;
    int wr = wave >> 1, wc = wave & 1;       // 2x2 waves, each 64x64 output
    int kh = lane >> 5, l31 = lane & 31;     // K-half, row/col-in-tile

    f32x16 acc[2][2];
    acc[0][0] = (f32x16)0.0f; acc[0][1] = (f32x16)0.0f;
    acc[1][0] = (f32x16)0.0f; acc[1][1] = (f32x16)0.0f;

    // staging: per call c (0..1): thread t -> row c*64 + (t>>2), LDS byte c*4096 + t*16,
    // swizzled source piece = (t&3) ^ ((row ^ (row>>2)) & 3)  [row&3, (row>>2)&3 same for both calls]
    int srow = t >> 2;
    int sp   = (t & 3) ^ ((srow ^ (srow >> 2)) & 3);
    const unsigned char* gA = reps + (size_t)(brow + srow) * DIM + sp * 16;
    const unsigned char* gB = reps + (size_t)(bcol + srow) * DIM + sp * 16;

    auto stage = [&](unsigned char* Ab, unsigned char* Bb, int k0) {
        #pragma unroll
        for (int c = 0; c < 2; c++) {
            async16(gA + k0 + c * 64 * DIM, Ab + t * 16 + c * 4096);
            async16(gB + k0 + c * 64 * DIM, Bb + t * 16 + c * 4096);
        }
    };

    // fragment rows + loop-invariant swizzled LDS byte offsets
    // (row+32 preserves both (r&3) and ((r>>2)&3), so swz is shared)
    int ra0 = wr * 64 + l31;
    int rb0 = wc * 64 + l31;
    int swa = (ra0 ^ (ra0 >> 2)) & 3;
    int swb = (rb0 ^ (rb0 >> 2)) & 3;
    int p0  = kh * 2;                        // this lane's K-half = pieces {p0, p0+1}
    int oa0l = ra0 * 64 + ((p0 ^ swa) * 16);
    int oa0h = ra0 * 64 + (((p0 + 1) ^ swa) * 16);
    int oa1l = oa0l + 32 * 64, oa1h = oa0h + 32 * 64;
    int ob0l = rb0 * 64 + ((p0 ^ swb) * 16);
    int ob0h = rb0 * 64 + (((p0 + 1) ^ swb) * 16);
    int ob1l = ob0l + 32 * 64, ob1h = ob0h + 32 * 64;

    auto ldf = [&](const unsigned char* base, int ol, int oh) -> i32x8 {
        i32x4 lo = *(const i32x4*)(base + ol);
        i32x4 hi = *(const i32x4*)(base + oh);
        i32x8 r;
        r[0] = lo[0]; r[1] = lo[1]; r[2] = lo[2]; r[3] = lo[3];
        r[4] = hi[0]; r[5] = hi[1]; r[6] = hi[2]; r[7] = hi[3];
        return r;
    };

    auto compute = [&](const unsigned char* Ab, const unsigned char* Bb) {
        i32x8 a0 = ldf(Ab, oa0l, oa0h);
        i32x8 a1 = ldf(Ab, oa1l, oa1h);
        i32x8 b0 = ldf(Bb, ob0l, ob0h);
        i32x8 b1 = ldf(Bb, ob1l, ob1h);
        acc[0][0] = __builtin_amdgcn_mfma_scale_f32_32x32x64_f8f6f4(
            a0, b0, acc[0][0], 0, 0, 0, SCALE1, 0, SCALE1);
        acc[0][1] = __builtin_amdgcn_mfma_scale_f32_32x32x64_f8f6f4(
            a0, b1, acc[0][1], 0, 0, 0, SCALE1, 0, SCALE1);
        acc[1][0] = __builtin_amdgcn_mfma_scale_f32_32x32x64_f8f6f4(
            a1, b0, acc[1][0], 0, 0, 0, SCALE1, 0, SCALE1);
        acc[1][1] = __builtin_amdgcn_mfma_scale_f32_32x32x64_f8f6f4(
            a1, b1, acc[1][1], 0, 0, 0, SCALE1, 0, SCALE1);
    };

    // prologue: two tiles in flight (8 DMAs outstanding per wave)
    stage(As0, Bs0, 0);
    stage(As1, Bs1, BK);

    #pragma unroll
    for (int k = 0; k < KITERS; k++) {
        unsigned char* Ac = (k & 1) ? As1 : As0;
        unsigned char* Bc = (k & 1) ? Bs1 : Bs0;
        if (k < KITERS - 1) WAITVM(4); else WAITVM(0);   // drain loads(k), keep loads(k+1) in flight
        BARRIER();                         // all waves' loads(k) landed
        compute(Ac, Bc);
        BARRIER();                         // all waves done reading buf(k)
        if (k + 2 < KITERS) stage(Ac, Bc, (k + 2) * BK);
    }

    // epilogue: 32x32 C/D layout col=lane&31, row=(reg&3)+8*(reg>>2)+4*(lane>>5)
    bool haspos = (bj - bi == 32);   // |rg-cg|==4096 only possible then (at rl==cl)
    int cl0 = wc * 64 + l31, cl1 = cl0 + 32;
    int labc0 = target[(bcol + cl0) & (B_SIZE - 1)];
    int labc1 = target[(bcol + cl1) & (B_SIZE - 1)];

    float colacc0 = 0.0f, colacc1 = 0.0f;
    #pragma unroll
    for (int mi = 0; mi < 2; mi++) {
        #pragma unroll
        for (int g = 0; g < 4; g++) {
            #pragma unroll
            for (int j = 0; j < 4; j++) {
                int reg = g * 4 + j;
                int rl = wr * 64 + mi * 32 + g * 8 + kh * 4 + j;
                int labr = target[(brow + rl) & (B_SIZE - 1)];
                bool pp0 = haspos && (rl == cl0);
                bool pp1 = haspos && (rl == cl1);
                float e0 = ((labr == labc0) && !pp0)
                               ? 0.0f
                               : __builtin_amdgcn_exp2f(acc[mi][0][reg] * EXP_SCALE);
                float e1 = ((labr == labc1) && !pp1)
                               ? 0.0f
                               : __builtin_amdgcn_exp2f(acc[mi][1][reg] * EXP_SCALE);
                colacc0 += e0; colacc1 += e1;
                float racc = e0 + e1;
                racc += __shfl_xor(racc, 1, 64);
                racc += __shfl_xor(racc, 2, 64);
                racc += __shfl_xor(racc, 4, 64);
                racc += __shfl_xor(racc, 8, 64);
                racc += __shfl_xor(racc, 16, 64);
                if (l31 == 0) atomicAdd(&denom[brow + rl], racc);
            }
        }
    }
    if (bi != bj) {
        colacc0 += __shfl_xor(colacc0, 32, 64);
        colacc1 += __shfl_xor(colacc1, 32, 64);
        if (lane < 32) {
            atomicAdd(&denom[bcol + cl0], colacc0);
            atomicAdd(&denom[bcol + cl1], colacc1);
        }
    }
}

// ---------- kernel 3: final loss (parallel, atomic accumulate into pre-zeroed out) ----------
__global__ __launch_bounds__(256) void loss_kernel(
    const float* __restrict__ denom, const float* __restrict__ pos,
    float* __restrict__ out)
{
    __shared__ float sc[4];
    int t = threadIdx.x, b = blockIdx.x;
    int i = b * 256 + t;
    float v = logf(denom[i] + 1e-7f);                  // 32 blocks x 256 = 8192
    float p = (i < B_SIZE) ? pos[i] : 0.0f;
    // loss = (sum log(denom) - (2/t) * sum pos) / 2B ; 2/t = 4
    float v2 = v - 4.0f * p;
    #pragma unroll
    for (int o = 32; o > 0; o >>= 1) v2 += __shfl_down(v2, o, 64);
    int lane = t & 63, w = t >> 6;
    if (lane == 0) sc[w] = v2;
    __syncthreads();
    if (t == 0) atomicAdd(out, (sc[0] + sc[1] + sc[2] + sc[3]) * (1.0f / (float)TWO_B));
}

// ---------- launcher ----------
extern "C" void kernel_launch(void* const* d_in, const int* in_sizes, int n_in,
                              void* d_out, int out_size, void* d_ws, size_t ws_size,
                              hipStream_t stream)
{
    const float* emb_i  = (const float*)d_in[0];
    const float* emb_j  = (const float*)d_in[1];
    const int*   target = (const int*)d_in[2];
    float* out = (float*)d_out;

    char* ws = (char*)d_ws;
    unsigned char* reps = (unsigned char*)ws;                        // 8192*512 = 4 MB (fp8)
    float* pos   = (float*)(ws + (size_t)TWO_B * DIM);               // 16 KB
    float* denom = (float*)(ws + (size_t)TWO_B * DIM + B_SIZE * 4);  // 32 KB

    norm_pos_kernel<<<B_SIZE, 256, 0, stream>>>(emb_i, emb_j, reps, pos, denom, out);
    sim_denom_kernel<<<NPAIRS, 256, 0, stream>>>(reps, target, denom);
    loss_kernel<<<TWO_B / 256, 256, 0, stream>>>(denom, pos, out);
}

// Round 2
// 134.151 us; speedup vs baseline: 1.7074x; 1.7074x over previous
//
#include <hip/hip_runtime.h>
#include <hip/hip_bf16.h>
#include <cstdint>

#define B_SIZE 4096
#define TWO_B  8192
#define DIM    512           // row length; fp8 => 512 bytes per row
#define NPAIRS 2080          // 64*65/2 upper-triangular tile pairs
// exp(x/t) = exp2(x * log2(e)/t), t = 0.5
#define EXP_SCALE 2.8853900817779268f

typedef __attribute__((ext_vector_type(4))) float f32x4;

// raw waitcnt: vmcnt(n) with lgkmcnt/expcnt unconstrained (gfx9 encoding)
#define WAITVM(n) __builtin_amdgcn_s_waitcnt(0xF70 | (n))
#define BARRIER() __builtin_amdgcn_s_barrier()

// ---------- helpers ----------
__device__ __forceinline__ void async16(const void* g, void* l) {
    __builtin_amdgcn_global_load_lds(
        (const __attribute__((address_space(1))) unsigned int*)g,
        (__attribute__((address_space(3))) unsigned int*)l,
        16, 0, 0);
}

// ---------- kernel 1: L2-normalize rows -> fp8 reps, fp32 positives, zero denom/out ----------
__global__ __launch_bounds__(256) void norm_pos_kernel(
    const float* __restrict__ emb_i, const float* __restrict__ emb_j,
    unsigned char* __restrict__ reps, float* __restrict__ pos,
    float* __restrict__ denom, float* __restrict__ out)
{
    __shared__ float sc[3][4];
    int b = blockIdx.x, t = threadIdx.x;
    if (b < 32) denom[b * 256 + t] = 0.0f;     // zero-init, visible at kernel boundary
    if (b == 32 && t == 0) out[0] = 0.0f;      // loss kernel accumulates atomically

    const float2* ri = (const float2*)(emb_i + (size_t)b * DIM);
    const float2* rj = (const float2*)(emb_j + (size_t)b * DIM);
    float2 xi = ri[t], xj = rj[t];
    float si = xi.x * xi.x + xi.y * xi.y;
    float sj = xj.x * xj.x + xj.y * xj.y;
    #pragma unroll
    for (int o = 32; o > 0; o >>= 1) { si += __shfl_down(si, o, 64); sj += __shfl_down(sj, o, 64); }
    int lane = t & 63, w = t >> 6;
    if (lane == 0) { sc[0][w] = si; sc[1][w] = sj; }
    __syncthreads();
    float ni2 = sc[0][0] + sc[0][1] + sc[0][2] + sc[0][3];
    float nj2 = sc[1][0] + sc[1][1] + sc[1][2] + sc[1][3];
    float rni = 1.0f / fmaxf(sqrtf(ni2), 1e-12f);
    float rnj = 1.0f / fmaxf(sqrtf(nj2), 1e-12f);
    float zix = xi.x * rni, ziy = xi.y * rni;
    float zjx = xj.x * rnj, zjy = xj.y * rnj;
    // pack 2 floats -> 2 OCP e4m3 bytes (HW cvt, gfx950)
    int pki = __builtin_amdgcn_cvt_pk_fp8_f32(zix, ziy, 0, false);
    int pkj = __builtin_amdgcn_cvt_pk_fp8_f32(zjx, zjy, 0, false);
    ((unsigned short*)(reps + (size_t)b * DIM))[t]            = (unsigned short)pki;
    ((unsigned short*)(reps + (size_t)(b + B_SIZE) * DIM))[t] = (unsigned short)pkj;
    float d = zix * zjx + ziy * zjy;
    #pragma unroll
    for (int o = 32; o > 0; o >>= 1) d += __shfl_down(d, o, 64);
    if (lane == 0) sc[2][w] = d;
    __syncthreads();
    if (t == 0) pos[b] = sc[2][0] + sc[2][1] + sc[2][2] + sc[2][3];
}

// ---------- kernel 2: symmetric fused R*R^T (fp8 MFMA) + masked exp row/col sums ----------
// fp8 tiles: 128 rows x 64 B; row r = 4 pieces of 16 B, piece p stored at p ^ ((r^(r>>2))&3)
// => fragment reads are 2-way bank aliased only (free).
// Pipeline: 3-buffer rotation (48 KB LDS), 2 tiles in flight, counted vmcnt(4),
// ONE barrier per K-iter: stage(k+2) writes buf (k+2)%3 == (k-1)%3, which every wave
// finished reading before this iter's top barrier -> trailing barrier eliminated.
#define BM 128
#define BK 64
#define KITERS 8             // DIM / BK

__global__ __launch_bounds__(256) void sim_denom_kernel(
    const unsigned char* __restrict__ reps,
    const int* __restrict__ target,
    float* __restrict__ denom)
{
    __shared__ __align__(16) unsigned char As[3][BM * BK];
    __shared__ __align__(16) unsigned char Bs[3][BM * BK];

    int t = threadIdx.x;
    // XCD-chunked remap: blockIdx round-robins across 8 XCDs; give each XCD a
    // contiguous 260-run of supertile-ordered ids (2080 = 8*260, bijective).
    int id0 = blockIdx.x;
    int id = (id0 & 7) * 260 + (id0 >> 3);

    // --- supertile swizzle: 4x4 supertiles of 16x16 tiles over the 64-tile triangle ---
    const int sI[10]  = {0,0,0,0,1,1,1,2,2,3};
    const int sJ[10]  = {0,1,2,3,1,2,3,2,3,3};
    const int off[11] = {0,136,392,648,904,1040,1296,1552,1688,1944,2080};
    int s = 0;
    while (off[s + 1] <= id) s++;
    int l = id - off[s];
    int u, v;
    if (sI[s] == sJ[s]) {                       // triangular 16x16: start(u)=u*(33-u)/2
        u = 0;
        while (((u + 1) * (32 - u)) / 2 <= l) u++;
        v = u + (l - (u * (33 - u)) / 2);
    } else { u = l >> 4; v = l & 15; }
    int bi = sI[s] * 16 + u;
    int bj = sJ[s] * 16 + v;
    int brow = bi * BM;
    int bcol = bj * BM;

    int wave = t >> 6, lane = t & 63;
    int wr = wave >> 1, wc = wave & 1;       // 2x2 waves, each 64x64 output
    int quad = lane >> 4, lm = lane & 15;

    f32x4 acc[4][4];
    #pragma unroll
    for (int i = 0; i < 4; i++)
        #pragma unroll
        for (int j = 0; j < 4; j++) acc[i][j] = (f32x4)0.0f;

    // staging: per call c (0..1): thread t -> row c*64 + (t>>2), LDS byte c*4096 + t*16,
    // swizzled source piece = (t&3) ^ ((row ^ (row>>2)) & 3)  [row&3, (row>>2)&3 same for both calls]
    int srow = t >> 2;
    int sp   = (t & 3) ^ ((srow ^ (srow >> 2)) & 3);
    const unsigned char* gA = reps + (size_t)(brow + srow) * DIM + sp * 16;
    const unsigned char* gB = reps + (size_t)(bcol + srow) * DIM + sp * 16;

    auto stage = [&](unsigned char* Ab, unsigned char* Bb, int k0) {
        #pragma unroll
        for (int c = 0; c < 2; c++) {
            async16(gA + k0 + c * 64 * DIM, Ab + t * 16 + c * 4096);
            async16(gB + k0 + c * 64 * DIM, Bb + t * 16 + c * 4096);
        }
    };
    auto compute = [&](const unsigned char* Ab, const unsigned char* Bb) {
        #pragma unroll
        for (int ss = 0; ss < 2; ss++) {       // two K=32 sub-steps of BK=64
            long af[4], bf[4];
            #pragma unroll
            for (int mi = 0; mi < 4; mi++) {
                int rl = wr * 64 + mi * 16 + lm;
                int p = (ss * 2 + (quad >> 1)) ^ ((rl ^ (rl >> 2)) & 3);
                af[mi] = *(const long*)(Ab + rl * 64 + p * 16 + (quad & 1) * 8);
            }
            #pragma unroll
            for (int ni = 0; ni < 4; ni++) {
                int cl = wc * 64 + ni * 16 + lm;
                int p = (ss * 2 + (quad >> 1)) ^ ((cl ^ (cl >> 2)) & 3);
                bf[ni] = *(const long*)(Bb + cl * 64 + p * 16 + (quad & 1) * 8);
            }
            #pragma unroll
            for (int mi = 0; mi < 4; mi++)
                #pragma unroll
                for (int ni = 0; ni < 4; ni++)
                    acc[mi][ni] = __builtin_amdgcn_mfma_f32_16x16x32_fp8_fp8(
                        af[mi], bf[ni], acc[mi][ni], 0, 0, 0);
        }
    };

    // prologue: two tiles in flight (8 DMAs outstanding per wave)
    stage(As[0], Bs[0], 0);
    stage(As[1], Bs[1], BK);

    #pragma unroll
    for (int k = 0; k < KITERS; k++) {
        if (k < KITERS - 1) WAITVM(4); else WAITVM(0);   // drain loads(k), keep loads(k+1) in flight
        BARRIER();                         // all waves' loads(k) landed; all done reading buf (k-1)%3
        compute(As[k % 3], Bs[k % 3]);
        if (k + 2 < KITERS) stage(As[(k + 2) % 3], Bs[(k + 2) % 3], (k + 2) * BK);
    }

    // epilogue: C/D layout col=lane&15, row=quad*4+reg; labels read direct (L2-hot)
    bool haspos = (bj - bi == 32);   // |rg-cg|==4096 only possible then (at rl==cl)
    int labc[4];
    #pragma unroll
    for (int ni = 0; ni < 4; ni++)
        labc[ni] = target[(bcol + wc * 64 + ni * 16 + lm) & (B_SIZE - 1)];

    float colacc[4] = {0.f, 0.f, 0.f, 0.f};
    #pragma unroll
    for (int mi = 0; mi < 4; mi++) {
        #pragma unroll
        for (int r = 0; r < 4; r++) {
            int rl = wr * 64 + mi * 16 + quad * 4 + r;
            int labr = target[(brow + rl) & (B_SIZE - 1)];
            float rowacc = 0.0f;
            #pragma unroll
            for (int ni = 0; ni < 4; ni++) {
                int cl = wc * 64 + ni * 16 + lm;
                bool pospair = haspos && (rl == cl);
                bool masked = (labr == labc[ni]) && !pospair;
                float e = masked ? 0.0f
                                 : __builtin_amdgcn_exp2f(acc[mi][ni][r] * EXP_SCALE);
                rowacc += e;
                colacc[ni] += e;
            }
            rowacc += __shfl_xor(rowacc, 1, 64);
            rowacc += __shfl_xor(rowacc, 2, 64);
            rowacc += __shfl_xor(rowacc, 4, 64);
            rowacc += __shfl_xor(rowacc, 8, 64);
            if (lm == 0) atomicAdd(&denom[brow + rl], rowacc);
        }
    }
    if (bi != bj) {
        #pragma unroll
        for (int ni = 0; ni < 4; ni++) {
            float c = colacc[ni];
            c += __shfl_xor(c, 16, 64);
            c += __shfl_xor(c, 32, 64);
            if (lane < 16) atomicAdd(&denom[bcol + wc * 64 + ni * 16 + lm], c);
        }
    }
}

// ---------- kernel 3: final loss (parallel, atomic accumulate into pre-zeroed out) ----------
__global__ __launch_bounds__(256) void loss_kernel(
    const float* __restrict__ denom, const float* __restrict__ pos,
    float* __restrict__ out)
{
    __shared__ float sc[4];
    int t = threadIdx.x, b = blockIdx.x;
    int i = b * 256 + t;
    float v = logf(denom[i] + 1e-7f);                  // 32 blocks x 256 = 8192
    float p = (i < B_SIZE) ? pos[i] : 0.0f;
    // loss = (sum log(denom) - (2/t) * sum pos) / 2B ; 2/t = 4
    float v2 = v - 4.0f * p;
    #pragma unroll
    for (int o = 32; o > 0; o >>= 1) v2 += __shfl_down(v2, o, 64);
    int lane = t & 63, w = t >> 6;
    if (lane == 0) sc[w] = v2;
    __syncthreads();
    if (t == 0) atomicAdd(out, (sc[0] + sc[1] + sc[2] + sc[3]) * (1.0f / (float)TWO_B));
}

// ---------- launcher ----------
extern "C" void kernel_launch(void* const* d_in, const int* in_sizes, int n_in,
                              void* d_out, int out_size, void* d_ws, size_t ws_size,
                              hipStream_t stream)
{
    const float* emb_i  = (const float*)d_in[0];
    const float* emb_j  = (const float*)d_in[1];
    const int*   target = (const int*)d_in[2];
    float* out = (float*)d_out;

    char* ws = (char*)d_ws;
    unsigned char* reps = (unsigned char*)ws;                        // 8192*512 = 4 MB (fp8)
    float* pos   = (float*)(ws + (size_t)TWO_B * DIM);               // 16 KB
    float* denom = (float*)(ws + (size_t)TWO_B * DIM + B_SIZE * 4);  // 32 KB

    norm_pos_kernel<<<B_SIZE, 256, 0, stream>>>(emb_i, emb_j, reps, pos, denom, out);
    sim_denom_kernel<<<NPAIRS, 256, 0, stream>>>(reps, target, denom);
    loss_kernel<<<TWO_B / 256, 256, 0, stream>>>(denom, pos, out);
}

// Round 3
// 120.668 us; speedup vs baseline: 1.8982x; 1.1117x over previous
//
#include <hip/hip_runtime.h>
#include <hip/hip_bf16.h>
#include <cstdint>

#define B_SIZE 4096
#define TWO_B  8192
#define DIM    512           // row length; fp8 => 512 bytes per row
#define NPAIRS 2080          // 64*65/2 upper-triangular tile pairs
// exp(x/t) = exp2(x * log2(e)/t), t = 0.5
#define EXP_SCALE 2.8853900817779268f

typedef __attribute__((ext_vector_type(4))) float f32x4;

// raw waitcnt: vmcnt(n) with lgkmcnt/expcnt unconstrained (gfx9 encoding)
#define WAITVM(n) __builtin_amdgcn_s_waitcnt(0xF70 | (n))
#define BARRIER() __builtin_amdgcn_s_barrier()

// ---------- helpers ----------
__device__ __forceinline__ void async16(const void* g, void* l) {
    __builtin_amdgcn_global_load_lds(
        (const __attribute__((address_space(1))) unsigned int*)g,
        (__attribute__((address_space(3))) unsigned int*)l,
        16, 0, 0);
}

// ---------- kernel 1: L2-normalize rows -> fp8 reps, fp32 positives ----------
__global__ __launch_bounds__(256) void norm_pos_kernel(
    const float* __restrict__ emb_i, const float* __restrict__ emb_j,
    unsigned char* __restrict__ reps, float* __restrict__ pos,
    float* __restrict__ out)
{
    __shared__ float sc[3][4];
    int b = blockIdx.x, t = threadIdx.x;
    if (b == 0 && t == 0) out[0] = 0.0f;       // loss kernel accumulates atomically

    const float2* ri = (const float2*)(emb_i + (size_t)b * DIM);
    const float2* rj = (const float2*)(emb_j + (size_t)b * DIM);
    float2 xi = ri[t], xj = rj[t];
    float si = xi.x * xi.x + xi.y * xi.y;
    float sj = xj.x * xj.x + xj.y * xj.y;
    #pragma unroll
    for (int o = 32; o > 0; o >>= 1) { si += __shfl_down(si, o, 64); sj += __shfl_down(sj, o, 64); }
    int lane = t & 63, w = t >> 6;
    if (lane == 0) { sc[0][w] = si; sc[1][w] = sj; }
    __syncthreads();
    float ni2 = sc[0][0] + sc[0][1] + sc[0][2] + sc[0][3];
    float nj2 = sc[1][0] + sc[1][1] + sc[1][2] + sc[1][3];
    float rni = 1.0f / fmaxf(sqrtf(ni2), 1e-12f);
    float rnj = 1.0f / fmaxf(sqrtf(nj2), 1e-12f);
    float zix = xi.x * rni, ziy = xi.y * rni;
    float zjx = xj.x * rnj, zjy = xj.y * rnj;
    // pack 2 floats -> 2 OCP e4m3 bytes (HW cvt, gfx950)
    int pki = __builtin_amdgcn_cvt_pk_fp8_f32(zix, ziy, 0, false);
    int pkj = __builtin_amdgcn_cvt_pk_fp8_f32(zjx, zjy, 0, false);
    ((unsigned short*)(reps + (size_t)b * DIM))[t]            = (unsigned short)pki;
    ((unsigned short*)(reps + (size_t)(b + B_SIZE) * DIM))[t] = (unsigned short)pkj;
    float d = zix * zjx + ziy * zjy;
    #pragma unroll
    for (int o = 32; o > 0; o >>= 1) d += __shfl_down(d, o, 64);
    if (lane == 0) sc[2][w] = d;
    __syncthreads();
    if (t == 0) pos[b] = sc[2][0] + sc[2][1] + sc[2][2] + sc[2][3];
}

// ---------- kernel 2: symmetric fused R*R^T (fp8 MFMA) + masked exp row/col sums ----------
// 8 waves x 512 threads, each wave 64x32 of the 128x128 tile -> acc = 32 AGPR/wave,
// ~75 regs total => 6 waves/SIMD => 24 waves/CU resident (2x the 4-wave version).
// fp8 tiles: 128 rows x 64 B; row r = 4 pieces of 16 B, piece p stored at p ^ ((r^(r>>2))&3).
// 2-buffer / 2-barrier pipeline (verified), counted vmcnt(2), 2 tiles in flight.
// Epilogue: atomic-free. Tile (bi,bj) writes row-sums to part[bj][...], col-sums to
// part[bi][...]; every slot of part[64][8192] is written exactly once (row-group g,
// slice x: x>=g from tile (g,x) row-side, x<g from tile (x,g) col-side).
#define BM 128
#define BK 64
#define KITERS 8             // DIM / BK

__global__ __launch_bounds__(512) void sim_denom_kernel(
    const unsigned char* __restrict__ reps,
    const int* __restrict__ target,
    float* __restrict__ part)
{
    __shared__ __align__(16) unsigned char As0[BM * BK];
    __shared__ __align__(16) unsigned char As1[BM * BK];
    __shared__ __align__(16) unsigned char Bs0[BM * BK];
    __shared__ __align__(16) unsigned char Bs1[BM * BK];

    int t = threadIdx.x;
    // XCD-chunked remap: give each XCD a contiguous 260-run of supertile-ordered ids
    // (2080 = 8*260, bijective) -> halves FETCH_SIZE (measured r2).
    int id0 = blockIdx.x;
    int id = (id0 & 7) * 260 + (id0 >> 3);

    // --- supertile swizzle: 4x4 supertiles of 16x16 tiles over the 64-tile triangle ---
    const int sI[10]  = {0,0,0,0,1,1,1,2,2,3};
    const int sJ[10]  = {0,1,2,3,1,2,3,2,3,3};
    const int off[11] = {0,136,392,648,904,1040,1296,1552,1688,1944,2080};
    int s = 0;
    while (off[s + 1] <= id) s++;
    int l = id - off[s];
    int u, v;
    if (sI[s] == sJ[s]) {                       // triangular 16x16: start(u)=u*(33-u)/2
        u = 0;
        while (((u + 1) * (32 - u)) / 2 <= l) u++;
        v = u + (l - (u * (33 - u)) / 2);
    } else { u = l >> 4; v = l & 15; }
    int bi = sI[s] * 16 + u;
    int bj = sJ[s] * 16 + v;
    int brow = bi * BM;
    int bcol = bj * BM;

    int wave = t >> 6, lane = t & 63;
    int wr = wave >> 2, wc = wave & 3;       // 2x4 waves, each 64x32 output
    int quad = lane >> 4, lm = lane & 15;

    f32x4 acc[4][2];
    #pragma unroll
    for (int i = 0; i < 4; i++) {
        acc[i][0] = (f32x4)0.0f;
        acc[i][1] = (f32x4)0.0f;
    }

    // staging: thread t -> row t>>2 (512 threads cover all 128 rows), LDS byte t*16,
    // swizzled source piece = (t&3) ^ ((row ^ (row>>2)) & 3)
    int srow = t >> 2;
    int sp   = (t & 3) ^ ((srow ^ (srow >> 2)) & 3);
    const unsigned char* gA = reps + (size_t)(brow + srow) * DIM + sp * 16;
    const unsigned char* gB = reps + (size_t)(bcol + srow) * DIM + sp * 16;

    auto stage = [&](unsigned char* Ab, unsigned char* Bb, int k0) {
        async16(gA + k0, Ab + t * 16);
        async16(gB + k0, Bb + t * 16);
    };
    auto compute = [&](const unsigned char* Ab, const unsigned char* Bb) {
        #pragma unroll
        for (int ss = 0; ss < 2; ss++) {       // two K=32 sub-steps of BK=64
            long af[4], bf[2];
            #pragma unroll
            for (int mi = 0; mi < 4; mi++) {
                int rl = wr * 64 + mi * 16 + lm;
                int p = (ss * 2 + (quad >> 1)) ^ ((rl ^ (rl >> 2)) & 3);
                af[mi] = *(const long*)(Ab + rl * 64 + p * 16 + (quad & 1) * 8);
            }
            #pragma unroll
            for (int ni = 0; ni < 2; ni++) {
                int cl = wc * 32 + ni * 16 + lm;
                int p = (ss * 2 + (quad >> 1)) ^ ((cl ^ (cl >> 2)) & 3);
                bf[ni] = *(const long*)(Bb + cl * 64 + p * 16 + (quad & 1) * 8);
            }
            #pragma unroll
            for (int mi = 0; mi < 4; mi++)
                #pragma unroll
                for (int ni = 0; ni < 2; ni++)
                    acc[mi][ni] = __builtin_amdgcn_mfma_f32_16x16x32_fp8_fp8(
                        af[mi], bf[ni], acc[mi][ni], 0, 0, 0);
        }
    };

    // prologue: two tiles in flight (4 DMAs outstanding per wave)
    stage(As0, Bs0, 0);
    stage(As1, Bs1, BK);

    #pragma unroll
    for (int k = 0; k < KITERS; k++) {
        unsigned char* Ac = (k & 1) ? As1 : As0;
        unsigned char* Bc = (k & 1) ? Bs1 : Bs0;
        if (k < KITERS - 1) WAITVM(2); else WAITVM(0);   // drain loads(k), keep loads(k+1) in flight
        BARRIER();                         // all waves' loads(k) landed
        compute(Ac, Bc);
        BARRIER();                         // all waves done reading buf(k)
        if (k + 2 < KITERS) stage(Ac, Bc, (k + 2) * BK);
    }

    // ---------- epilogue: masked exp + row/col sums, atomic-free ----------
    // C/D layout: col=lane&15, row=quad*4+reg.
    // Cross-wave combine via LDS reuse: As0 (row partials, 4wc x 128) and Bs0
    // (col partials, 2wr x 128). Safe: As0/Bs0 last read in compute(k=6); all waves
    // passed k=7's top barrier, so those reads completed.
    bool haspos = (bj - bi == 32);   // |rg-cg|==4096 only possible then (at rl==cl)
    int labc[2];
    #pragma unroll
    for (int ni = 0; ni < 2; ni++)
        labc[ni] = target[(bcol + wc * 32 + ni * 16 + lm) & (B_SIZE - 1)];

    float* red_row = (float*)As0;    // [4][128] = 2 KB
    float* red_col = (float*)Bs0;    // [2][128] = 1 KB

    float colacc[2] = {0.f, 0.f};
    #pragma unroll
    for (int mi = 0; mi < 4; mi++) {
        #pragma unroll
        for (int r = 0; r < 4; r++) {
            int rl = wr * 64 + mi * 16 + quad * 4 + r;
            int labr = target[(brow + rl) & (B_SIZE - 1)];
            float rowacc = 0.0f;
            #pragma unroll
            for (int ni = 0; ni < 2; ni++) {
                int cl = wc * 32 + ni * 16 + lm;
                bool pospair = haspos && (rl == cl);
                bool masked = (labr == labc[ni]) && !pospair;
                float e = masked ? 0.0f
                                 : __builtin_amdgcn_exp2f(acc[mi][ni][r] * EXP_SCALE);
                rowacc += e;
                colacc[ni] += e;
            }
            rowacc += __shfl_xor(rowacc, 1, 64);
            rowacc += __shfl_xor(rowacc, 2, 64);
            rowacc += __shfl_xor(rowacc, 4, 64);
            rowacc += __shfl_xor(rowacc, 8, 64);
            if (lm == 0) red_row[wc * 128 + rl] = rowacc;   // one lane per quad, rows distinct
        }
    }
    #pragma unroll
    for (int ni = 0; ni < 2; ni++) {
        float c = colacc[ni];
        c += __shfl_xor(c, 16, 64);
        c += __shfl_xor(c, 32, 64);
        if (quad == 0) red_col[wr * 128 + wc * 32 + ni * 16 + lm] = c;
    }
    BARRIER();
    if (t < 128) {
        float rs = red_row[t] + red_row[128 + t] + red_row[256 + t] + red_row[384 + t];
        part[(size_t)bj * TWO_B + brow + t] = rs;
    } else if (t < 256) {
        if (bi != bj) {
            int c = t - 128;
            float cs = red_col[c] + red_col[128 + c];
            part[(size_t)bi * TWO_B + bcol + c] = cs;
        }
    }
}

// ---------- kernel 3: final loss (sum 64 part slices, then log/pos reduce) ----------
__global__ __launch_bounds__(256) void loss_kernel(
    const float* __restrict__ part, const float* __restrict__ pos,
    float* __restrict__ out)
{
    __shared__ float sc[4];
    int t = threadIdx.x, b = blockIdx.x;
    int i = b * 256 + t;
    float s = 0.0f;
    #pragma unroll
    for (int x = 0; x < 64; x++) s += part[(size_t)x * TWO_B + i];
    float v = logf(s + 1e-7f);                         // 32 blocks x 256 = 8192
    float p = (i < B_SIZE) ? pos[i] : 0.0f;
    // loss = (sum log(denom) - (2/t) * sum pos) / 2B ; 2/t = 4
    float v2 = v - 4.0f * p;
    #pragma unroll
    for (int o = 32; o > 0; o >>= 1) v2 += __shfl_down(v2, o, 64);
    int lane = t & 63, w = t >> 6;
    if (lane == 0) sc[w] = v2;
    __syncthreads();
    if (t == 0) atomicAdd(out, (sc[0] + sc[1] + sc[2] + sc[3]) * (1.0f / (float)TWO_B));
}

// ---------- launcher ----------
extern "C" void kernel_launch(void* const* d_in, const int* in_sizes, int n_in,
                              void* d_out, int out_size, void* d_ws, size_t ws_size,
                              hipStream_t stream)
{
    const float* emb_i  = (const float*)d_in[0];
    const float* emb_j  = (const float*)d_in[1];
    const int*   target = (const int*)d_in[2];
    float* out = (float*)d_out;

    char* ws = (char*)d_ws;
    unsigned char* reps = (unsigned char*)ws;                        // 8192*512 = 4 MB (fp8)
    float* pos   = (float*)(ws + (size_t)TWO_B * DIM);               // 16 KB
    float* part  = (float*)(ws + (size_t)TWO_B * DIM + B_SIZE * 4);  // 64*8192*4 = 2 MB

    norm_pos_kernel<<<B_SIZE, 256, 0, stream>>>(emb_i, emb_j, reps, pos, out);
    sim_denom_kernel<<<NPAIRS, 512, 0, stream>>>(reps, target, part);
    loss_kernel<<<TWO_B / 256, 256, 0, stream>>>(part, pos, out);
}